// Round 8
// baseline (142.407 us; speedup 1.0000x reference)
//
#include <hip/hip_runtime.h>
#include <hip/hip_bf16.h>
#include <stdint.h>

// ---------------------------------------------------------------------------
// Net_75282186764473 — forward == 'experiment' dynamics (stop_grad identity).
// Euler algebra: p0=0 -> q1=q0 -> D1=D0 -> p2=2*D0 (exact); last step's p is
// discarded -> 3 MFMA phases per stage: D(q0), D(q2), D(q3).
// q is kept PRE-SCALED in revolutions: qr = (1.1/2pi)*q, so sin(1.1*q) is a
// single v_sin_f32 (via __builtin_amdgcn_sinf). bf16 pack = +0x8000 round
// (<=0.5 ULP, same bound as RNE) + v_perm_b32. A = M'-fragments in registers
// (M' = dt*(c2q(W)+Qn-I); e folded as k=208 row driven by constant 1.0 in the
// sin buffer). Sin crosses waves via 3 LDS buffers (pow2 stride + XOR-block
// swizzle). 512-thr blocks, <=2 node-tiles/wave, batch=32/block.
// Single fused prep kernel (in-block diag + pack), 26 blocks.
// Output = fac * (2pi/1.1) * qr[:,196:206]  (65536 x 10 fp32).
// ---------------------------------------------------------------------------

typedef __attribute__((ext_vector_type(8))) short bh8;
typedef __attribute__((ext_vector_type(4))) float f32x4;

#define TILES 13        // node tiles of 16 -> 208 (>= 206)
#define KSTEPS 7        // k tiles of 32 -> 224 (k=208 is the e-row)
#define ROWDW 128       // dwords per LDS sin row (pow2; XOR swizzle on 16B blks)
#define BROWS 32        // batch rows per block
#define BUFDW (BROWS * ROWDW)     // 4096 dwords per buffer

#define K_QR 0.17507043f          // 1.1 / (2*pi)
#define K_PR 0.017507043f         // 0.1 * 1.1 / (2*pi)
#define K_OUT 5.7119866f          // 2*pi / 1.1

static __device__ __forceinline__ uint16_t bf16_bits(float v) {
    __hip_bfloat16 h = __float2bfloat16(v);
    return *reinterpret_cast<uint16_t*>(&h);
}

// Round-half-up bf16 pack of (s0,s1) -> uint32 [s1.bf16 : s0.bf16].
static __device__ __forceinline__ uint32_t pack_bf16_rh(float s0, float s1) {
    const uint32_t u0 = __float_as_uint(s0) + 0x8000u;
    const uint32_t u1 = __float_as_uint(s1) + 0x8000u;
    return __builtin_amdgcn_perm(u1, u0, 0x07060302u);
}

// Fused prep: one block per (stage,tile). Phase 1: coalesced col+row sums of C
// for the tile's 16 columns -> c2q diagonal. Phase 2: pack A-frags of
// M' = dt*(c2q(C)+Qn-I) plus e-row at k==208:
// frag[((st*13+tile)*7+ks)*64+lane] = 8 bf16, elem j = M'[k][n],
//   k = ks*32+quad*8+j, n = tile*16+(lane&15).
__global__ void prep_pack(const float* __restrict__ C1, const float* __restrict__ Qn1,
                          const float* __restrict__ e1,
                          const float* __restrict__ C2, const float* __restrict__ Qn2,
                          const float* __restrict__ e2,
                          uint16_t* __restrict__ frag) {
    const int bid = blockIdx.x;                 // 0..25
    const int st = bid / TILES, tile = bid % TILES;
    const float* C  = st ? C2 : C1;
    const float* Qn = st ? Qn2 : Qn1;
    const float* e  = st ? e2 : e1;
    const int N = st ? 206 : 196;
    const int t = threadIdx.x;                  // 256
    __shared__ float part_col[16][17];
    __shared__ float part_row[16][17];
    __shared__ float dsh[16];
    {   // col sums: 16-lane groups sweep 16 consecutive cols of row i
        const int col = t & 15, seg = t >> 4;
        const int n = tile * 16 + col;
        float sc = 0.f;
        if (n < N)
            for (int i = seg; i < N; i += 16) sc += C[i * N + n];
        part_col[col][seg] = sc;
        // row sums: 16-lane groups sweep consecutive i within row n2
        const int row = t >> 4, ii = t & 15;
        const int n2 = tile * 16 + row;
        float sr = 0.f;
        if (n2 < N)
            for (int i = ii; i < N; i += 16) sr += C[n2 * N + i];
        part_row[row][ii] = sr;
    }
    __syncthreads();
    if (t < 16) {
        float d = 0.f;
        #pragma unroll
        for (int j = 0; j < 16; ++j) d += part_col[t][j] + part_row[t][j];
        dsh[t] = -0.5f * d;
    }
    __syncthreads();
    const int lane = t & 63, grp = t >> 6;
    const int quad = (lane >> 4) & 3;
    const int n = tile * 16 + (lane & 15);
    for (int ks = grp; ks < KSTEPS; ks += 4) {
        union { uint16_t v16[8]; uint4 v128; } vals;
        #pragma unroll
        for (int j = 0; j < 8; ++j) {
            const int k = ks * 32 + quad * 8 + j;
            float v = 0.f;
            if (n < N) {
                if (k < N) {
                    if (k == n) v = dsh[lane & 15] + Qn[n * N + n] - 1.0f;
                    else        v = 0.5f * (C[k * N + n] + C[n * N + k]) + Qn[k * N + n];
                    v *= 0.1f;                  // fold dt
                } else if (k == 208) {
                    v = 0.1f * e[n];            // e-row (sin row 208 == 1.0)
                }
            }
            vals.v16[j] = bf16_bits(v);
        }
        const size_t off = ((size_t)(st * TILES + tile) * KSTEPS + ks) * 64 + lane;
        reinterpret_cast<uint4*>(frag)[off] = vals.v128;
    }
}

__global__ __launch_bounds__(512, 4) void pat_main(
    const float* __restrict__ x, const uint16_t* __restrict__ frag,
    const float* __restrict__ fac, float* __restrict__ out) {
    __shared__ __align__(16) uint32_t sinb[3 * BUFDW];    // 49,152 B
    const int tid = threadIdx.x;
    const int lane = tid & 63;
    const int w = __builtin_amdgcn_readfirstlane(tid >> 6);   // 0..7
    const int c = lane & 15, quad = lane >> 4;
    const uint32_t cs = (uint32_t)(c & 7);                    // XOR swizzle
    const long batch0 = (long)blockIdx.x * BROWS + c;         // bt=0; +16 for bt=1
    // wave w<5 owns tiles {w, w+8}; waves 5..7 own {w}. Tile 12 -> wave 4.
    const int t0 = w, t1 = w + 8;
    const int ntiles = (w < 5) ? 2 : 1;

    // zero all 3 buffers (covers pad rows k=209..223 and swizzle spill)
    {
        uint4 z; z.x = 0; z.y = 0; z.z = 0; z.w = 0;
        #pragma unroll
        for (int i = 0; i < 6; ++i)
            reinterpret_cast<uint4*>(sinb)[tid + i * 512] = z;
    }

    const bh8* fragv = reinterpret_cast<const bh8*>(frag);
    bh8 A[2][KSTEPS];
    #pragma unroll
    for (int nt = 0; nt < 2; ++nt)
        if (nt < ntiles) {
            const int tile = nt ? t1 : t0;
            #pragma unroll
            for (int ks = 0; ks < KSTEPS; ++ks)
                A[nt][ks] = fragv[((size_t)tile * KSTEPS + ks) * 64 + lane];
        }

    // q kept pre-scaled in revolutions: qr = K_QR * q
    float q[2][2][4];
    f32x4 P[2][2];
    #pragma unroll
    for (int nt = 0; nt < 2; ++nt) {
        const int n0 = (nt ? t1 : t0) * 16 + quad * 4;
        #pragma unroll
        for (int bt = 0; bt < 2; ++bt) {
            const long batch = batch0 + bt * 16;
            if (nt < ntiles && n0 + 3 < 196) {
                const float4 v = *reinterpret_cast<const float4*>(x + batch * 196 + n0);
                q[nt][bt][0] = K_QR * v.x; q[nt][bt][1] = K_QR * v.y;
                q[nt][bt][2] = K_QR * v.z; q[nt][bt][3] = K_QR * v.w;
            } else {
                #pragma unroll
                for (int r = 0; r < 4; ++r) q[nt][bt][r] = 0.f;
            }
            #pragma unroll
            for (int r = 0; r < 4; ++r) P[nt][bt][r] = 0.f;
        }
    }
    const float fout = fac[0] * K_OUT;

    auto sin_phase = [&](int buf) {
        #pragma unroll
        for (int nt = 0; nt < 2; ++nt)
            if (nt < ntiles) {
                const int tile = nt ? t1 : t0;
                const uint32_t blk = ((uint32_t)(tile * 2 + (quad >> 1))) ^ cs;
                #pragma unroll
                for (int bt = 0; bt < 2; ++bt) {
                    uint2 u;
                    u.x = pack_bf16_rh(__builtin_amdgcn_sinf(q[nt][bt][0]),
                                       __builtin_amdgcn_sinf(q[nt][bt][1]));
                    u.y = pack_bf16_rh(__builtin_amdgcn_sinf(q[nt][bt][2]),
                                       __builtin_amdgcn_sinf(q[nt][bt][3]));
                    *reinterpret_cast<uint2*>(
                        &sinb[buf * BUFDW + (c + bt * 16) * ROWDW
                              + blk * 4 + (quad & 1) * 2]) = u;
                }
            }
    };
    auto mfma_phase = [&](int buf) {
        #pragma unroll
        for (int ks = 0; ks < KSTEPS; ++ks) {
            const uint32_t koff = (((uint32_t)(ks * 4 + quad)) ^ cs) * 4;
            const bh8 b0 = *reinterpret_cast<const bh8*>(
                &sinb[buf * BUFDW + c * ROWDW + koff]);
            const bh8 b1 = *reinterpret_cast<const bh8*>(
                &sinb[buf * BUFDW + (c + 16) * ROWDW + koff]);
            #pragma unroll
            for (int nt = 0; nt < 2; ++nt)
                if (nt < ntiles) {
                    P[nt][0] = __builtin_amdgcn_mfma_f32_16x16x32_bf16(A[nt][ks], b0, P[nt][0], 0, 0, 0);
                    P[nt][1] = __builtin_amdgcn_mfma_f32_16x16x32_bf16(A[nt][ks], b1, P[nt][1], 0, 0, 0);
                }
        }
    };
    auto q_update = [&]() {      // qr += (dt*1.1/2pi) * P   (P carries one dt)
        #pragma unroll
        for (int nt = 0; nt < 2; ++nt)
            if (nt < ntiles)
                #pragma unroll
                for (int bt = 0; bt < 2; ++bt)
                    #pragma unroll
                    for (int r = 0; r < 4; ++r)
                        q[nt][bt][r] += K_PR * P[nt][bt][r];
    };

    __syncthreads();                       // zeros visible
    // constant 1.0 at sin element k=208 (e-drive), all 3 bufs x 32 batch rows
    if (tid < 96) {
        const int bb = tid >> 5, cc = tid & 31;
        sinb[bb * BUFDW + cc * ROWDW + (26u ^ (uint32_t)(cc & 7)) * 4] = 0x3F80u;
    }
    sin_phase(0);                          // sin(q0) -> bufA
    __syncthreads();

    for (int stg = 0; stg < 2; ++stg) {
        mfma_phase(0);                     // P = D0  (p1)
        q_update();                        // q2 = q0 + 0.1*D0   (q1 == q0)
        sin_phase(1);                      // sin(q2) -> bufB
        #pragma unroll
        for (int nt = 0; nt < 2; ++nt)
            #pragma unroll
            for (int bt = 0; bt < 2; ++bt)
                #pragma unroll
                for (int r = 0; r < 4; ++r)
                    P[nt][bt][r] += P[nt][bt][r];               // p2 = 2*D0
        q_update();                        // q3
        sin_phase(2);                      // sin(q3) -> bufC
        __syncthreads();
        mfma_phase(1);                     // p3
        q_update();                        // q4
        mfma_phase(2);                     // p4
        if (stg == 0) {                    // prefetch stage-2 A into freed regs
            #pragma unroll
            for (int nt = 0; nt < 2; ++nt)
                if (nt < ntiles) {
                    const int tile = nt ? t1 : t0;
                    #pragma unroll
                    for (int ks = 0; ks < KSTEPS; ++ks)
                        A[nt][ks] = fragv[((size_t)(TILES + tile) * KSTEPS + ks) * 64 + lane];
                }
        }
        q_update();                        // q5 (stage-final q)
        if (stg == 0) {
            #pragma unroll
            for (int nt = 0; nt < 2; ++nt)
                #pragma unroll
                for (int bt = 0; bt < 2; ++bt)
                    #pragma unroll
                    for (int r = 0; r < 4; ++r) P[nt][bt][r] = 0.f;  // p resets
            sin_phase(0);                  // sin(q5) -> bufA for stage 2
            __syncthreads();
        }
    }

    // outputs: nodes 196..205 live in tile 12 = wave 4's nt=1
    if (w == 4) {
        const int n0 = 192 + quad * 4;
        #pragma unroll
        for (int r = 0; r < 4; ++r) {
            const int node = n0 + r;
            if (node >= 196 && node < 206) {
                out[batch0 * 10 + (node - 196)]        = fout * q[1][0][r];
                out[(batch0 + 16) * 10 + (node - 196)] = fout * q[1][1][r];
            }
        }
    }
}

extern "C" void kernel_launch(void* const* d_in, const int* in_sizes, int n_in,
                              void* d_out, int out_size, void* d_ws, size_t ws_size,
                              hipStream_t stream) {
    const float* x   = (const float*)d_in[0];
    const float* w1  = (const float*)d_in[1];
    const float* b1  = (const float*)d_in[2];
    const float* w2  = (const float*)d_in[3];
    const float* b2  = (const float*)d_in[4];
    const float* fac = (const float*)d_in[5];
    const float* qn1 = (const float*)d_in[6];
    const float* qn2 = (const float*)d_in[7];
    float* out = (float*)d_out;

    uint16_t* frg = (uint16_t*)d_ws;       // 182 KB

    prep_pack<<<2 * TILES, 256, 0, stream>>>(w1, qn1, b1, w2, qn2, b2, frg);

    const int B = in_sizes[0] / 196;       // 65536
    pat_main<<<B / BROWS, 512, 0, stream>>>(x, frg, fac, out);
}